// Round 7
// baseline (365.526 us; speedup 1.0000x reference)
//
#include <hip/hip_runtime.h>
#include <stdint.h>

#define DIMC 1024
#define HEADS 16
#define HD 64
#define HIDDENC 4096
#define BATCH 2
#define SEQ 2048
#define MTOK (BATCH*SEQ)

typedef __bf16 bf16x8 __attribute__((ext_vector_type(8)));
typedef float f32x4 __attribute__((ext_vector_type(4)));

__device__ __forceinline__ float bf2f(unsigned short u) {
    union { unsigned int u; float f; } v; v.u = ((unsigned int)u) << 16; return v.f;
}
__device__ __forceinline__ unsigned short f2bf(float f) {
    union { float f; unsigned int u; } v; v.f = f;
    unsigned int r = v.u + 0x7fffu + ((v.u >> 16) & 1u);
    return (unsigned short)(r >> 16);
}
// pack 2 f32 -> 2 bf16 (RNE), src0 -> low half (T12 recipe, guide-verified)
__device__ __forceinline__ unsigned int cvt_pk_bf16(float lo, float hi) {
    unsigned int r;
    asm("v_cvt_pk_bf16_f32 %0, %1, %2" : "=v"(r) : "v"(lo), "v"(hi));
    return r;
}
// 2^x (log2e is pre-folded into the Q scale)
__device__ __forceinline__ float exp2_fast(float x) {
#if __has_builtin(__builtin_amdgcn_exp2f)
    return __builtin_amdgcn_exp2f(x);
#else
    float r;
    asm("v_exp_f32 %0, %1" : "=v"(r) : "v"(x));
    return r;
#endif
}

#define GLOAD_LDS(g, l) \
    __builtin_amdgcn_global_load_lds( \
        (const __attribute__((address_space(1))) void*)(g), \
        (__attribute__((address_space(3))) void*)(l), 16, 0, 0)

// ---------------------------------------------------------------------------
// Fused weight transposes: fp32 (K x N) -> bf16 (N x K) for all 4 weights.
// ---------------------------------------------------------------------------
__device__ __forceinline__ void tp_tile(const float* __restrict__ in,
                                        unsigned short* __restrict__ out,
                                        int K, int N, int tn, int tk, int tid,
                                        unsigned short (*tile)[65]) {
    for (int c = tid; c < 1024; c += 256) {
        int r = c >> 4, coff = (c & 15) * 4;
        float4 v = *(const float4*)(in + (size_t)(tk + r) * N + tn + coff);
        tile[r][coff + 0] = f2bf(v.x);
        tile[r][coff + 1] = f2bf(v.y);
        tile[r][coff + 2] = f2bf(v.z);
        tile[r][coff + 3] = f2bf(v.w);
    }
    __syncthreads();
    for (int c = tid; c < 512; c += 256) {
        int rn = c >> 3, off = (c & 7) * 8;
        unsigned short tmp[8];
        #pragma unroll
        for (int j = 0; j < 8; j++) tmp[j] = tile[off + j][rn];
        *(uint4*)(out + (size_t)(tn + rn) * K + tk + off) = *(uint4*)tmp;
    }
}

__global__ __launch_bounds__(256) void fused_transpose(
    const float* __restrict__ qkvw, const float* __restrict__ projw,
    const float* __restrict__ fc1w, const float* __restrict__ fc2w,
    unsigned short* __restrict__ qkv_wT, unsigned short* __restrict__ proj_wT,
    unsigned short* __restrict__ fc1_wT, unsigned short* __restrict__ fc2_wT) {
    __shared__ unsigned short tile[64][65];
    int id = blockIdx.x, tid = threadIdx.x;
    if (id < 768) {
        tp_tile(qkvw, qkv_wT, 1024, 3072, (id % 48) * 64, (id / 48) * 64, tid, tile);
    } else if (id < 1024) {
        id -= 768;
        tp_tile(projw, proj_wT, 1024, 1024, (id % 16) * 64, (id / 16) * 64, tid, tile);
    } else if (id < 2048) {
        id -= 1024;
        tp_tile(fc1w, fc1_wT, 1024, 4096, (id % 64) * 64, (id / 64) * 64, tid, tile);
    } else {
        id -= 2048;
        tp_tile(fc2w, fc2_wT, 4096, 1024, (id % 16) * 64, (id / 16) * 64, tid, tile);
    }
}

// ---------------------------------------------------------------------------
// LayerNorm: f32 input, f32 w/b, bf16 output. One block per row (DIMC=1024).
// ---------------------------------------------------------------------------
__global__ __launch_bounds__(256) void ln_kernel(const float* __restrict__ inp,
                                                 const float* __restrict__ w,
                                                 const float* __restrict__ b,
                                                 unsigned short* __restrict__ out) {
    int row = blockIdx.x;
    int tid = threadIdx.x;
    int base = tid * 4;
    float4 v = *(const float4*)(inp + (size_t)row * DIMC + base);
    float x[4] = {v.x, v.y, v.z, v.w};
    float s1 = x[0] + x[1] + x[2] + x[3];
    float s2 = x[0]*x[0] + x[1]*x[1] + x[2]*x[2] + x[3]*x[3];
    #pragma unroll
    for (int off = 32; off > 0; off >>= 1) {
        s1 += __shfl_xor(s1, off);
        s2 += __shfl_xor(s2, off);
    }
    __shared__ float red[8];
    int wv = tid >> 6;
    if ((tid & 63) == 0) { red[wv] = s1; red[4 + wv] = s2; }
    __syncthreads();
    s1 = red[0] + red[1] + red[2] + red[3];
    s2 = red[4] + red[5] + red[6] + red[7];
    float mean = s1 * (1.0f / DIMC);
    float var  = s2 * (1.0f / DIMC) - mean * mean;
    float rstd = rsqrtf(var + 1e-5f);
    float4 wv4 = *(const float4*)(w + base);
    float4 bv4 = *(const float4*)(b + base);
    ushort4 o;
    o.x = f2bf((x[0] - mean) * rstd * wv4.x + bv4.x);
    o.y = f2bf((x[1] - mean) * rstd * wv4.y + bv4.y);
    o.z = f2bf((x[2] - mean) * rstd * wv4.z + bv4.z);
    o.w = f2bf((x[3] - mean) * rstd * wv4.w + bv4.w);
    *(ushort4*)(out + (size_t)row * DIMC + base) = o;
}

// ---------------------------------------------------------------------------
// bf16 MFMA GEMM: C(M x N) = A(M x K) @ BT(N x K)^T.
// Tile TM x TN, 4 waves (2x2), XOR-swizzled LDS, global_load_lds staging,
// double-buffered with counted vmcnt (R4).
//
// Mapping (A/B-measured):
//  - QKV/FC1 (TM=TN=128): 2D dim3 grid (R4 mapping). R5 rectangle REGRESSED
//    FC1 66->79 (co-resident blocks lockstep-read the same A-panel lines);
//    dim3 spreads co-resident blocks over different m-rows.
//  - PROJ/FC2 (TN=64): 1D XCD rectangle (MG=4 x NG=2). R4 evidence: naive
//    dim3 put each m-tile's n-blocks on all 8 XCDs -> A-dup=8, FETCH 143MB.
// ---------------------------------------------------------------------------
enum { EP_QKV = 0, EP_PROJ = 1, EP_FC1 = 2, EP_FC2 = 3 };

template <int MODE, int N, int K, int TM, int TN, int BK>
__global__ __launch_bounds__(256) void gemm_kernel(
    const unsigned short* __restrict__ A,
    const unsigned short* __restrict__ BT,
    const float* __restrict__ bias,
    const float* __restrict__ res,      // fp32 residual (PROJ: x, FC2: x1)
    void* __restrict__ out0,
    unsigned short* __restrict__ q_buf,
    unsigned short* __restrict__ k_buf,
    unsigned short* __restrict__ v_buf) {  // QKV: vT_buf [bh][d][t]
    constexpr int MI = TM / 32;          // m-fragments per wave (2 waves in m)
    constexpr int NJ = TN / 32;          // n-fragments per wave (2 waves in n)
    constexpr int CPR = BK / 8;
    constexpr int NT = K / BK;
    constexpr int N_LD = (TM + TN) * BK / 2048;  // gload_lds per thread per tile
    static_assert(N_LD == 8 || N_LD == 4, "vmcnt literal");
    constexpr int NX = N / TN;
    constexpr int NY = MTOK / TM;
    constexpr int MG = 4, NG = 2;        // XCD rectangle partition (PROJ/FC2)
    constexpr int NXG = NX / NG, NYG = NY / MG;

    __shared__ __align__(16) unsigned short As[2 * TM * BK];
    __shared__ __align__(16) unsigned short Bs[2 * TN * BK];
    const int tid = threadIdx.x;

    int m0, n0;
    if constexpr (MODE == EP_PROJ || MODE == EP_FC2) {
        // 1D grid, consecutive ids round-robin XCDs -> rectangle per XCD
        const int jb = blockIdx.x;
        const int xcd = jb & 7;
        const int tb = jb >> 3;
        const int mg = xcd >> 1, ng = xcd & 1;
        m0 = (mg * NYG + tb / NXG) * TM;
        n0 = (ng * NXG + tb % NXG) * TN;
    } else {
        m0 = blockIdx.y * TM;
        n0 = blockIdx.x * TN;
    }

    const int wave = tid >> 6, lane = tid & 63;
    const int wm = wave >> 1, wn = wave & 1;
    const int quad = lane >> 4, l16 = lane & 15;
    const int swz = l16 & (CPR - 1);

    f32x4 acc[MI][NJ] = {};

    auto stage = [&](int t, int b) {
        const size_t kk = (size_t)t * BK;
        #pragma unroll
        for (int it = 0; it < TM * BK / 2048; ++it) {
            int c = tid + 256 * it;
            int row = c / CPR, jj = c % CPR;
            int col8 = (jj ^ (row & (CPR - 1))) * 8;
            GLOAD_LDS(A + (size_t)(m0 + row) * K + kk + col8,
                      As + (size_t)b * TM * BK + (size_t)c * 8);
        }
        #pragma unroll
        for (int it = 0; it < TN * BK / 2048; ++it) {
            int c = tid + 256 * it;
            int row = c / CPR, jj = c % CPR;
            int col8 = (jj ^ (row & (CPR - 1))) * 8;
            GLOAD_LDS(BT + (size_t)(n0 + row) * K + kk + col8,
                      Bs + (size_t)b * TN * BK + (size_t)c * 8);
        }
    };

    stage(0, 0);
    for (int t = 0; t < NT; ++t) {
        const int cur = t & 1;
        if (t + 1 < NT) {
            stage(t + 1, cur ^ 1);
            // wait tile t's N_LD loads; leave tile t+1's in flight (never 0)
            if constexpr (N_LD == 8) asm volatile("s_waitcnt vmcnt(8)" ::: "memory");
            else                     asm volatile("s_waitcnt vmcnt(4)" ::: "memory");
        } else {
            asm volatile("s_waitcnt vmcnt(0)" ::: "memory");
        }
        __builtin_amdgcn_s_barrier();

        const unsigned short* Asb = As + (size_t)cur * TM * BK;
        const unsigned short* Bsb = Bs + (size_t)cur * TN * BK;
        #pragma unroll
        for (int kk2 = 0; kk2 < BK / 32; ++kk2) {
            bf16x8 af[MI], bfv[NJ];
            #pragma unroll
            for (int i = 0; i < MI; i++) {
                int row = 16 * MI * wm + 16 * i + l16;
                int sj = (4 * kk2 + quad) ^ swz;
                af[i] = *(const bf16x8*)&Asb[row * BK + sj * 8];
            }
            #pragma unroll
            for (int j = 0; j < NJ; j++) {
                int row = 16 * NJ * wn + 16 * j + l16;
                int sj = (4 * kk2 + quad) ^ swz;
                bfv[j] = *(const bf16x8*)&Bsb[row * BK + sj * 8];
            }
            #pragma unroll
            for (int i = 0; i < MI; i++)
                #pragma unroll
                for (int j = 0; j < NJ; j++)
                    acc[i][j] = __builtin_amdgcn_mfma_f32_16x16x32_bf16(af[i], bfv[j], acc[i][j], 0, 0, 0);
        }
        // all this wave's ds_reads complete (results consumed), then barrier so
        // next iter's stage into buf[cur] can't race other waves' reads.
        asm volatile("s_waitcnt lgkmcnt(0)" ::: "memory");
        __builtin_amdgcn_s_barrier();
    }

    #pragma unroll
    for (int i = 0; i < MI; i++) {
        #pragma unroll
        for (int j = 0; j < NJ; j++) {
            int nl = n0 + 16 * NJ * wn + 16 * j + l16;
            if (MODE == EP_QKV) {
                int which = nl >> 10, rem = nl & 1023;
                int hh = rem >> 6, d = rem & 63;
                int ml0 = m0 + 16 * MI * wm + 16 * i + quad * 4;  // r=0..3 -> t0..t0+3
                int bb2 = ml0 >> 11, t0 = ml0 & 2047;
                int bh = bb2 * HEADS + hh;
                if (which == 2) {
                    // V written TRANSPOSED [bh][d][t]: 4 consecutive t -> one 8B store
                    uint2 w;
                    w.x = cvt_pk_bf16(acc[i][j][0], acc[i][j][1]);
                    w.y = cvt_pk_bf16(acc[i][j][2], acc[i][j][3]);
                    *(uint2*)(v_buf + ((size_t)bh * HD + d) * SEQ + t0) = w;
                } else if (which == 0) {
                    // q pre-scale = (1/8)*log2(e) so softmax is a bare v_exp_f32 (2^x)
                    #pragma unroll
                    for (int r = 0; r < 4; r++)
                        q_buf[((size_t)bh * SEQ + t0 + r) * HD + d] =
                            f2bf(acc[i][j][r] * 0.18033688011112042f);
                } else {
                    #pragma unroll
                    for (int r = 0; r < 4; r++)
                        k_buf[((size_t)bh * SEQ + t0 + r) * HD + d] = f2bf(acc[i][j][r]);
                }
            } else {
                float bval = bias[nl];
                #pragma unroll
                for (int r = 0; r < 4; r++) {
                    int ml = m0 + 16 * MI * wm + 16 * i + quad * 4 + r;
                    float v = acc[i][j][r];
                    if (MODE == EP_PROJ) {
                        float* x1 = (float*)out0;
                        x1[(size_t)ml * DIMC + nl] = res[(size_t)ml * DIMC + nl] + v + bval;
                    } else if (MODE == EP_FC1) {
                        float g = v + bval;
                        float u = 1.5957691216f * (g + 0.044715f * g * g * g);
                        float gv = g / (1.0f + __expf(-u));
                        ((unsigned short*)out0)[(size_t)ml * HIDDENC + nl] = f2bf(gv);
                    } else {
                        ((float*)out0)[(size_t)ml * DIMC + nl] =
                            res[(size_t)ml * DIMC + nl] + v + bval;
                    }
                }
            }
        }
    }
}

// ---------------------------------------------------------------------------
// FUSED causal flash attention: one block per (qt, bh), kt = 0..qt in-block.
// Round 7: replaces split-K partials + combine. R6 evidence: K/V L2-resident
// per XCD (FETCH 22.7MB ~= ideal), so fine-grained split-K only paid overhead:
// 2560 prologues, 21MB O_part write + 21MB re-read + a whole combine kernel.
// Normalization is now in-register: lsum is complete per block; butterfly +
// __shfl redistributes row sums to the PV C-layout rows.
//
// Key-padding semantics MUST match the reference's fp32 "+(-1e9)": masked keys
// get CONSTANT weight 1e-13 (uniform when a row is fully masked). Causal diag
// zeroing as before. Swapped QK^T (S^T=mfma(K,Q)) -> P-store = 2x cvt_pk +
// 1x ds_write_b64 per ct; PV A-read = contiguous ds_read_b128 from the
// XOR-swizzled row-major Ps[q][key]. Output staged through LDS -> full-line
// coalesced stores. Grid: qt DESCENDING (long blocks first), bh pinned to XCD.
// ---------------------------------------------------------------------------
#define KP 72
#define PMASK 1e-13f
__global__ __launch_bounds__(256, 6) void attn_fused(
    const unsigned short* __restrict__ q_buf,
    const unsigned short* __restrict__ k_buf,
    const unsigned short* __restrict__ vT_buf,
    const int* __restrict__ mask,
    unsigned short* __restrict__ attn_o) {
    __shared__ __align__(16) unsigned short Ks[64 * KP];
    __shared__ __align__(16) unsigned short Vs[64 * KP];
    __shared__ __align__(16) unsigned short Ps[4 * 16 * 64];  // per-wave swizzled P[q][key]; O-stage after loop
    __shared__ __align__(16) float Msf[64];

    // decode: xcd = j&7 pins bh group to XCD (R3-verified round-robin);
    // qt descends with j so the longest blocks (qt=31: 32 tiles) start first.
    const int j = blockIdx.x;
    const int xcd = j & 7;
    const int t = j >> 3;              // 0..127
    const int bhg = t & 3;
    const int qt = 31 - (t >> 2);
    const int bh = bhg * 8 + xcd;      // 0..31
    const int bb = bh >> 4, h = bh & 15;
    const int kt1 = qt + 1;

    const int tid = threadIdx.x, wave = tid >> 6, lane = tid & 63;
    const int quad = lane >> 4, l16 = lane & 15;
    const unsigned short* qp = q_buf + (size_t)bh * SEQ * HD;
    const unsigned short* kp = k_buf + (size_t)bh * SEQ * HD;
    const unsigned short* vp = vT_buf + (size_t)bh * HD * SEQ;
    const int* mrow_ptr = mask + bb * SEQ;

    const int qrow = qt * 64 + wave * 16 + l16;   // this lane's q (global)
    bf16x8 qf[2];
    qf[0] = *(const bf16x8*)(qp + (size_t)qrow * HD + 8 * quad);
    qf[1] = *(const bf16x8*)(qp + (size_t)qrow * HD + 32 + 8 * quad);

    f32x4 o[4] = {};
    float lsum = 0.0f;

    const int r0 = tid >> 3, c0 = (tid & 7) * 8;
    const int r1 = r0 + 32;

    // per-wave swizzled Ps addressing (bytes): row = q = l16, 128 B rows
    char* psb = (char*)Ps + wave * 2048 + l16 * 128;
    const int swz = (l16 & 7) << 4;

    // prefetch first tile; Msf holds 1.0 = masked, 0.0 = visible
    uint4 pk0, pk1, pv0, pv1; float pmv = 0.0f;
    pk0 = *(const uint4*)(kp + (size_t)r0 * HD + c0);
    pk1 = *(const uint4*)(kp + (size_t)r1 * HD + c0);
    pv0 = *(const uint4*)(vp + (size_t)r0 * SEQ + c0);
    pv1 = *(const uint4*)(vp + (size_t)r1 * SEQ + c0);
    if (tid < 64) pmv = mrow_ptr[tid] ? 1.0f : 0.0f;

    for (int kt = 0; kt < kt1; kt++) {
        __syncthreads();
        *(uint4*)&Ks[r0 * KP + c0] = pk0;
        *(uint4*)&Ks[r1 * KP + c0] = pk1;
        *(uint4*)&Vs[r0 * KP + c0] = pv0;
        *(uint4*)&Vs[r1 * KP + c0] = pv1;
        if (tid < 64) Msf[tid] = pmv;
        if (kt + 1 < kt1) {
            pk0 = *(const uint4*)(kp + (size_t)((kt + 1) * 64 + r0) * HD + c0);
            pk1 = *(const uint4*)(kp + (size_t)((kt + 1) * 64 + r1) * HD + c0);
            pv0 = *(const uint4*)(vp + (size_t)r0 * SEQ + (kt + 1) * 64 + c0);
            pv1 = *(const uint4*)(vp + (size_t)r1 * SEQ + (kt + 1) * 64 + c0);
            if (tid < 64) pmv = mrow_ptr[(kt + 1) * 64 + tid] ? 1.0f : 0.0f;
        }
        __syncthreads();

        // S^T = K @ Q^T : sc[ct][r] = S[key=16ct+4quad+r][q=l16]
        f32x4 sc[4];
        __builtin_amdgcn_s_setprio(1);
        #pragma unroll
        for (int ct = 0; ct < 4; ct++) {
            f32x4 z = {};
            #pragma unroll
            for (int ss = 0; ss < 2; ss++) {
                bf16x8 kf = *(const bf16x8*)&Ks[(16 * ct + l16) * KP + 32 * ss + 8 * quad];
                z = __builtin_amdgcn_mfma_f32_16x16x32_bf16(kf, qf[ss], z, 0, 0, 0);
            }
            sc[ct] = z;
        }
        __builtin_amdgcn_s_setprio(0);

        const bool diag = (kt == qt);
        #pragma unroll
        for (int ct = 0; ct < 4; ct++) {
            float4 mq = *(const float4*)&Msf[16 * ct + 4 * quad];
            float mfs[4] = {mq.x, mq.y, mq.z, mq.w};
            const int kg0 = kt * 64 + 16 * ct + 4 * quad;
            float pv4[4];
            #pragma unroll
            for (int r = 0; r < 4; r++) {
                float p = (mfs[r] != 0.0f) ? PMASK : exp2_fast(sc[ct][r]);
                if (diag && (kg0 + r) > qrow) p = 0.0f;
                lsum += p;
                pv4[r] = p;
            }
            uint2 w;
            w.x = cvt_pk_bf16(pv4[0], pv4[1]);
            w.y = cvt_pk_bf16(pv4[2], pv4[3]);
            // P[q=l16][key=16ct+4quad .. +3]: logical byte quad*8+ct*32, swizzled
            *(uint2*)(psb + ((quad * 8 + ct * 32) ^ swz)) = w;
        }
        asm volatile("" ::: "memory");   // order punned LDS write -> read

        __builtin_amdgcn_s_setprio(1);
        #pragma unroll
        for (int ss = 0; ss < 2; ss++) {
            bf16x8 pf = *(const bf16x8*)(psb + ((ss * 64 + quad * 16) ^ swz));
            #pragma unroll
            for (int dt = 0; dt < 4; dt++) {
                bf16x8 vf = *(const bf16x8*)&Vs[(16 * dt + l16) * KP + 32 * ss + 8 * quad];
                o[dt] = __builtin_amdgcn_mfma_f32_16x16x32_bf16(pf, vf, o[dt], 0, 0, 0);
            }
        }
        __builtin_amdgcn_s_setprio(0);
    }

    // complete row sums: butterfly over quads -> every lane holds sum for q=l16
    lsum += __shfl_xor(lsum, 16);
    lsum += __shfl_xor(lsum, 32);
    // redistribute to PV C-layout rows: this lane's o rows are quad*4+r
    float linv[4];
    #pragma unroll
    for (int r = 0; r < 4; r++) linv[r] = 1.0f / __shfl(lsum, quad * 4 + r);

    // normalized output staged through the wave's private Ps region (dead now),
    // then 2x dwordx4 per lane -> full-line coalesced stores to attn_o.
    unsigned short* Ls = Ps + wave * 1024;   // 16 rows x 64 cols bf16 = 2 KB
    #pragma unroll
    for (int dt = 0; dt < 4; dt++)
        #pragma unroll
        for (int r = 0; r < 4; r++)
            Ls[(quad * 4 + r) * 64 + 16 * dt + l16] = f2bf(o[dt][r] * linv[r]);
    asm volatile("" ::: "memory");           // order punned LDS write -> read
    unsigned short* ob = attn_o + ((size_t)(bb * SEQ + qt * 64 + wave * 16)) * DIMC + h * HD;
    const int rlo = lane >> 3, dlo = (lane & 7) * 8;
    *(uint4*)(ob + (size_t)rlo * DIMC + dlo) = *(const uint4*)&Ls[lane * 8];
    *(uint4*)(ob + (size_t)(rlo + 8) * DIMC + dlo) = *(const uint4*)&Ls[512 + lane * 8];
}

// ---------------------------------------------------------------------------
extern "C" void kernel_launch(void* const* d_in, const int* in_sizes, int n_in,
                              void* d_out, int out_size, void* d_ws, size_t ws_size,
                              hipStream_t stream) {
    const float* x     = (const float*)d_in[0];
    const int*   mask  = (const int*)d_in[1];
    const float* ln1w  = (const float*)d_in[2];
    const float* ln1b  = (const float*)d_in[3];
    const float* qkvw  = (const float*)d_in[4];
    const float* projw = (const float*)d_in[5];
    const float* projb = (const float*)d_in[6];
    const float* ln2w  = (const float*)d_in[7];
    const float* ln2b  = (const float*)d_in[8];
    const float* fc1w  = (const float*)d_in[9];
    const float* fc1b  = (const float*)d_in[10];
    const float* fc2w  = (const float*)d_in[11];
    const float* fc2b  = (const float*)d_in[12];

    // Workspace (80 MB, lifetime reuse):
    //  [0,6M)    qkv_wT (dead after QKV gemm)
    //  [6,8M)    proj_wT
    //  [8,16M)   fc1_wT
    //  [16,24M)  fc2_wT
    //  [24,32M)  ln_buf (ln1, later ln2)
    //  [32,40M)  q_buf   | h_buf [32,64M) at FC1
    //  [40,48M)  k_buf
    //  [48,56M)  attn_o (fused attention output)
    //  [56,64M)  vT_buf (written directly by QKV, transposed)
    //  [64,80M)  x1 fp32
    char* base = (char*)d_ws;
    unsigned short* qkv_wT  = (unsigned short*)(base);
    unsigned short* proj_wT = (unsigned short*)(base + (size_t)6  * 1024 * 1024);
    unsigned short* fc1_wT  = (unsigned short*)(base + (size_t)8  * 1024 * 1024);
    unsigned short* fc2_wT  = (unsigned short*)(base + (size_t)16 * 1024 * 1024);
    unsigned short* ln_buf  = (unsigned short*)(base + (size_t)24 * 1024 * 1024);
    unsigned short* q_buf   = (unsigned short*)(base + (size_t)32 * 1024 * 1024);
    unsigned short* k_buf   = (unsigned short*)(base + (size_t)40 * 1024 * 1024);
    unsigned short* attn_o  = (unsigned short*)(base + (size_t)48 * 1024 * 1024);
    unsigned short* vT_buf  = (unsigned short*)(base + (size_t)56 * 1024 * 1024);
    unsigned short* h_buf   = (unsigned short*)(base + (size_t)32 * 1024 * 1024); // reuse
    float*          x1      = (float*)(base + (size_t)64 * 1024 * 1024);

    // 1. all 4 weight transposes in one launch
    fused_transpose<<<3072, 256, 0, stream>>>(qkvw, projw, fc1w, fc2w,
                                              qkv_wT, proj_wT, fc1_wT, fc2_wT);

    // 2. LN1 (fp32 x -> bf16)
    ln_kernel<<<MTOK, 256, 0, stream>>>(x, ln1w, ln1b, ln_buf);

    // 3. QKV GEMM -> q (pre-scaled by log2e/8), k [bh][t][d]; V DIRECTLY
    //    transposed into vT_buf [bh][d][t] (packed 8B stores).
    gemm_kernel<EP_QKV, 3072, 1024, 128, 128, 64><<<dim3(24, 32), 256, 0, stream>>>(
        ln_buf, qkv_wT, nullptr, nullptr, nullptr, q_buf, k_buf, vT_buf);

    // 4. fused attention (1024 blocks: one per (qt,bh), qt descending,
    //    bh pinned to XCD) -> attn_o
    attn_fused<<<1024, 256, 0, stream>>>(q_buf, k_buf, vT_buf, mask, attn_o);

    // 5. proj GEMM + residual(x fp32) -> x1
    gemm_kernel<EP_PROJ, 1024, 1024, 64, 64, 64><<<1024, 256, 0, stream>>>(
        attn_o, proj_wT, projb, x, x1, nullptr, nullptr, nullptr);

    // 6. LN2 (fp32 x1 -> bf16)
    ln_kernel<<<MTOK, 256, 0, stream>>>(x1, ln2w, ln2b, ln_buf);

    // 7. FC1 + GELU -> h_buf (bf16)
    gemm_kernel<EP_FC1, 4096, 1024, 128, 128, 64><<<dim3(32, 32), 256, 0, stream>>>(
        ln_buf, fc1_wT, fc1b, nullptr, h_buf, nullptr, nullptr, nullptr);

    // 8. FC2 + residual(x1) -> d_out
    gemm_kernel<EP_FC2, 1024, 4096, 64, 64, 64><<<1024, 256, 0, stream>>>(
        h_buf, fc2_wT, fc2b, x1, d_out, nullptr, nullptr, nullptr);
}

// Round 8
// 345.802 us; speedup vs baseline: 1.0570x; 1.0570x over previous
//
#include <hip/hip_runtime.h>
#include <stdint.h>

#define DIMC 1024
#define HEADS 16
#define HD 64
#define HIDDENC 4096
#define BATCH 2
#define SEQ 2048
#define MTOK (BATCH*SEQ)

typedef __bf16 bf16x8 __attribute__((ext_vector_type(8)));
typedef float f32x4 __attribute__((ext_vector_type(4)));

__device__ __forceinline__ float bf2f(unsigned short u) {
    union { unsigned int u; float f; } v; v.u = ((unsigned int)u) << 16; return v.f;
}
__device__ __forceinline__ unsigned short f2bf(float f) {
    union { float f; unsigned int u; } v; v.f = f;
    unsigned int r = v.u + 0x7fffu + ((v.u >> 16) & 1u);
    return (unsigned short)(r >> 16);
}
// pack 2 f32 -> 2 bf16 (RNE), src0 -> low half (T12 recipe, guide-verified)
__device__ __forceinline__ unsigned int cvt_pk_bf16(float lo, float hi) {
    unsigned int r;
    asm("v_cvt_pk_bf16_f32 %0, %1, %2" : "=v"(r) : "v"(lo), "v"(hi));
    return r;
}
// 2^x (log2e is pre-folded into the Q scale)
__device__ __forceinline__ float exp2_fast(float x) {
#if __has_builtin(__builtin_amdgcn_exp2f)
    return __builtin_amdgcn_exp2f(x);
#else
    float r;
    asm("v_exp_f32 %0, %1" : "=v"(r) : "v"(x));
    return r;
#endif
}

#define GLOAD_LDS(g, l) \
    __builtin_amdgcn_global_load_lds( \
        (const __attribute__((address_space(1))) void*)(g), \
        (__attribute__((address_space(3))) void*)(l), 16, 0, 0)

// ---------------------------------------------------------------------------
// Fused weight transposes: fp32 (K x N) -> bf16 (N x K) for all 4 weights.
// ---------------------------------------------------------------------------
__device__ __forceinline__ void tp_tile(const float* __restrict__ in,
                                        unsigned short* __restrict__ out,
                                        int K, int N, int tn, int tk, int tid,
                                        unsigned short (*tile)[65]) {
    for (int c = tid; c < 1024; c += 256) {
        int r = c >> 4, coff = (c & 15) * 4;
        float4 v = *(const float4*)(in + (size_t)(tk + r) * N + tn + coff);
        tile[r][coff + 0] = f2bf(v.x);
        tile[r][coff + 1] = f2bf(v.y);
        tile[r][coff + 2] = f2bf(v.z);
        tile[r][coff + 3] = f2bf(v.w);
    }
    __syncthreads();
    for (int c = tid; c < 512; c += 256) {
        int rn = c >> 3, off = (c & 7) * 8;
        unsigned short tmp[8];
        #pragma unroll
        for (int j = 0; j < 8; j++) tmp[j] = tile[off + j][rn];
        *(uint4*)(out + (size_t)(tn + rn) * K + tk + off) = *(uint4*)tmp;
    }
}

__global__ __launch_bounds__(256) void fused_transpose(
    const float* __restrict__ qkvw, const float* __restrict__ projw,
    const float* __restrict__ fc1w, const float* __restrict__ fc2w,
    unsigned short* __restrict__ qkv_wT, unsigned short* __restrict__ proj_wT,
    unsigned short* __restrict__ fc1_wT, unsigned short* __restrict__ fc2_wT) {
    __shared__ unsigned short tile[64][65];
    int id = blockIdx.x, tid = threadIdx.x;
    if (id < 768) {
        tp_tile(qkvw, qkv_wT, 1024, 3072, (id % 48) * 64, (id / 48) * 64, tid, tile);
    } else if (id < 1024) {
        id -= 768;
        tp_tile(projw, proj_wT, 1024, 1024, (id % 16) * 64, (id / 16) * 64, tid, tile);
    } else if (id < 2048) {
        id -= 1024;
        tp_tile(fc1w, fc1_wT, 1024, 4096, (id % 64) * 64, (id / 64) * 64, tid, tile);
    } else {
        id -= 2048;
        tp_tile(fc2w, fc2_wT, 4096, 1024, (id % 16) * 64, (id / 16) * 64, tid, tile);
    }
}

// ---------------------------------------------------------------------------
// LayerNorm: f32 input, f32 w/b, bf16 output. One block per row (DIMC=1024).
// ---------------------------------------------------------------------------
__global__ __launch_bounds__(256) void ln_kernel(const float* __restrict__ inp,
                                                 const float* __restrict__ w,
                                                 const float* __restrict__ b,
                                                 unsigned short* __restrict__ out) {
    int row = blockIdx.x;
    int tid = threadIdx.x;
    int base = tid * 4;
    float4 v = *(const float4*)(inp + (size_t)row * DIMC + base);
    float x[4] = {v.x, v.y, v.z, v.w};
    float s1 = x[0] + x[1] + x[2] + x[3];
    float s2 = x[0]*x[0] + x[1]*x[1] + x[2]*x[2] + x[3]*x[3];
    #pragma unroll
    for (int off = 32; off > 0; off >>= 1) {
        s1 += __shfl_xor(s1, off);
        s2 += __shfl_xor(s2, off);
    }
    __shared__ float red[8];
    int wv = tid >> 6;
    if ((tid & 63) == 0) { red[wv] = s1; red[4 + wv] = s2; }
    __syncthreads();
    s1 = red[0] + red[1] + red[2] + red[3];
    s2 = red[4] + red[5] + red[6] + red[7];
    float mean = s1 * (1.0f / DIMC);
    float var  = s2 * (1.0f / DIMC) - mean * mean;
    float rstd = rsqrtf(var + 1e-5f);
    float4 wv4 = *(const float4*)(w + base);
    float4 bv4 = *(const float4*)(b + base);
    ushort4 o;
    o.x = f2bf((x[0] - mean) * rstd * wv4.x + bv4.x);
    o.y = f2bf((x[1] - mean) * rstd * wv4.y + bv4.y);
    o.z = f2bf((x[2] - mean) * rstd * wv4.z + bv4.z);
    o.w = f2bf((x[3] - mean) * rstd * wv4.w + bv4.w);
    *(ushort4*)(out + (size_t)row * DIMC + base) = o;
}

// ---------------------------------------------------------------------------
// bf16 MFMA GEMM: C(M x N) = A(M x K) @ BT(N x K)^T.
// Tile TM x TN, 4 waves (2x2), XOR-swizzled LDS, global_load_lds staging,
// double-buffered with counted vmcnt (R4).
//
// Mapping (A/B-measured):
//  - QKV/FC1 (TM=TN=128): 2D dim3 grid (R4 mapping). R5 rectangle REGRESSED
//    FC1 66->79 (co-resident blocks lockstep-read the same A-panel lines);
//    dim3 spreads co-resident blocks over different m-rows.
//  - PROJ/FC2 (TN=64): 1D XCD rectangle (MG=4 x NG=2). R4 evidence: naive
//    dim3 put each m-tile's n-blocks on all 8 XCDs -> A-dup=8, FETCH 143MB.
// ---------------------------------------------------------------------------
enum { EP_QKV = 0, EP_PROJ = 1, EP_FC1 = 2, EP_FC2 = 3 };

template <int MODE, int N, int K, int TM, int TN, int BK>
__global__ __launch_bounds__(256) void gemm_kernel(
    const unsigned short* __restrict__ A,
    const unsigned short* __restrict__ BT,
    const float* __restrict__ bias,
    const float* __restrict__ res,      // fp32 residual (PROJ: x, FC2: x1)
    void* __restrict__ out0,
    unsigned short* __restrict__ q_buf,
    unsigned short* __restrict__ k_buf,
    unsigned short* __restrict__ v_buf) {  // QKV: vT_buf [bh][d][t]
    constexpr int MI = TM / 32;          // m-fragments per wave (2 waves in m)
    constexpr int NJ = TN / 32;          // n-fragments per wave (2 waves in n)
    constexpr int CPR = BK / 8;
    constexpr int NT = K / BK;
    constexpr int N_LD = (TM + TN) * BK / 2048;  // gload_lds per thread per tile
    static_assert(N_LD == 8 || N_LD == 4, "vmcnt literal");
    constexpr int NX = N / TN;
    constexpr int NY = MTOK / TM;
    constexpr int MG = 4, NG = 2;        // XCD rectangle partition (PROJ/FC2)
    constexpr int NXG = NX / NG, NYG = NY / MG;

    __shared__ __align__(16) unsigned short As[2 * TM * BK];
    __shared__ __align__(16) unsigned short Bs[2 * TN * BK];
    const int tid = threadIdx.x;

    int m0, n0;
    if constexpr (MODE == EP_PROJ || MODE == EP_FC2) {
        // 1D grid, consecutive ids round-robin XCDs -> rectangle per XCD
        const int jb = blockIdx.x;
        const int xcd = jb & 7;
        const int tb = jb >> 3;
        const int mg = xcd >> 1, ng = xcd & 1;
        m0 = (mg * NYG + tb / NXG) * TM;
        n0 = (ng * NXG + tb % NXG) * TN;
    } else {
        m0 = blockIdx.y * TM;
        n0 = blockIdx.x * TN;
    }

    const int wave = tid >> 6, lane = tid & 63;
    const int wm = wave >> 1, wn = wave & 1;
    const int quad = lane >> 4, l16 = lane & 15;
    const int swz = l16 & (CPR - 1);

    f32x4 acc[MI][NJ] = {};

    auto stage = [&](int t, int b) {
        const size_t kk = (size_t)t * BK;
        #pragma unroll
        for (int it = 0; it < TM * BK / 2048; ++it) {
            int c = tid + 256 * it;
            int row = c / CPR, jj = c % CPR;
            int col8 = (jj ^ (row & (CPR - 1))) * 8;
            GLOAD_LDS(A + (size_t)(m0 + row) * K + kk + col8,
                      As + (size_t)b * TM * BK + (size_t)c * 8);
        }
        #pragma unroll
        for (int it = 0; it < TN * BK / 2048; ++it) {
            int c = tid + 256 * it;
            int row = c / CPR, jj = c % CPR;
            int col8 = (jj ^ (row & (CPR - 1))) * 8;
            GLOAD_LDS(BT + (size_t)(n0 + row) * K + kk + col8,
                      Bs + (size_t)b * TN * BK + (size_t)c * 8);
        }
    };

    stage(0, 0);
    for (int t = 0; t < NT; ++t) {
        const int cur = t & 1;
        if (t + 1 < NT) {
            stage(t + 1, cur ^ 1);
            // wait tile t's N_LD loads; leave tile t+1's in flight (never 0)
            if constexpr (N_LD == 8) asm volatile("s_waitcnt vmcnt(8)" ::: "memory");
            else                     asm volatile("s_waitcnt vmcnt(4)" ::: "memory");
        } else {
            asm volatile("s_waitcnt vmcnt(0)" ::: "memory");
        }
        __builtin_amdgcn_s_barrier();

        const unsigned short* Asb = As + (size_t)cur * TM * BK;
        const unsigned short* Bsb = Bs + (size_t)cur * TN * BK;
        #pragma unroll
        for (int kk2 = 0; kk2 < BK / 32; ++kk2) {
            bf16x8 af[MI], bfv[NJ];
            #pragma unroll
            for (int i = 0; i < MI; i++) {
                int row = 16 * MI * wm + 16 * i + l16;
                int sj = (4 * kk2 + quad) ^ swz;
                af[i] = *(const bf16x8*)&Asb[row * BK + sj * 8];
            }
            #pragma unroll
            for (int j = 0; j < NJ; j++) {
                int row = 16 * NJ * wn + 16 * j + l16;
                int sj = (4 * kk2 + quad) ^ swz;
                bfv[j] = *(const bf16x8*)&Bsb[row * BK + sj * 8];
            }
            #pragma unroll
            for (int i = 0; i < MI; i++)
                #pragma unroll
                for (int j = 0; j < NJ; j++)
                    acc[i][j] = __builtin_amdgcn_mfma_f32_16x16x32_bf16(af[i], bfv[j], acc[i][j], 0, 0, 0);
        }
        // all this wave's ds_reads complete (results consumed), then barrier so
        // next iter's stage into buf[cur] can't race other waves' reads.
        asm volatile("s_waitcnt lgkmcnt(0)" ::: "memory");
        __builtin_amdgcn_s_barrier();
    }

    #pragma unroll
    for (int i = 0; i < MI; i++) {
        #pragma unroll
        for (int j = 0; j < NJ; j++) {
            int nl = n0 + 16 * NJ * wn + 16 * j + l16;
            if (MODE == EP_QKV) {
                int which = nl >> 10, rem = nl & 1023;
                int hh = rem >> 6, d = rem & 63;
                int ml0 = m0 + 16 * MI * wm + 16 * i + quad * 4;  // r=0..3 -> t0..t0+3
                int bb2 = ml0 >> 11, t0 = ml0 & 2047;
                int bh = bb2 * HEADS + hh;
                if (which == 2) {
                    // V written TRANSPOSED [bh][d][t]: 4 consecutive t -> one 8B store
                    uint2 w;
                    w.x = cvt_pk_bf16(acc[i][j][0], acc[i][j][1]);
                    w.y = cvt_pk_bf16(acc[i][j][2], acc[i][j][3]);
                    *(uint2*)(v_buf + ((size_t)bh * HD + d) * SEQ + t0) = w;
                } else if (which == 0) {
                    // q pre-scale = (1/8)*log2(e) so softmax is a bare v_exp_f32 (2^x)
                    #pragma unroll
                    for (int r = 0; r < 4; r++)
                        q_buf[((size_t)bh * SEQ + t0 + r) * HD + d] =
                            f2bf(acc[i][j][r] * 0.18033688011112042f);
                } else {
                    #pragma unroll
                    for (int r = 0; r < 4; r++)
                        k_buf[((size_t)bh * SEQ + t0 + r) * HD + d] = f2bf(acc[i][j][r]);
                }
            } else {
                float bval = bias[nl];
                #pragma unroll
                for (int r = 0; r < 4; r++) {
                    int ml = m0 + 16 * MI * wm + 16 * i + quad * 4 + r;
                    float v = acc[i][j][r];
                    if (MODE == EP_PROJ) {
                        float* x1 = (float*)out0;
                        x1[(size_t)ml * DIMC + nl] = res[(size_t)ml * DIMC + nl] + v + bval;
                    } else if (MODE == EP_FC1) {
                        float g = v + bval;
                        float u = 1.5957691216f * (g + 0.044715f * g * g * g);
                        float gv = g / (1.0f + __expf(-u));
                        ((unsigned short*)out0)[(size_t)ml * HIDDENC + nl] = f2bf(gv);
                    } else {
                        ((float*)out0)[(size_t)ml * DIMC + nl] =
                            res[(size_t)ml * DIMC + nl] + v + bval;
                    }
                }
            }
        }
    }
}

// ---------------------------------------------------------------------------
// FUSED causal flash attention, COMPLEMENTARY-PAIR balanced (Round 8).
// One block per (pair p, bh): q-tiles qa=31-p and qb=p. Total compute units
// per block = (qa+1)+(qb+1) = 33, EXACTLY uniform -> no critical-path skew
// (R7 evidence: variable-length blocks all co-resident -> runtime = longest
// block, occ 26%, dur 81). For kt <= qb both q-tiles consume the SAME staged
// K/V tile -> stage count per bh drops 528 -> 392 and MFMA-per-barrier doubles
// in the shared range. Grid 512, bh pinned to XCD.
//
// Key-padding semantics: masked keys get CONSTANT weight 1e-13 (matches ref
// fp32 "+(-1e9)": uniform softmax when a row is fully masked). Swapped QK^T
// (S^T=mfma(K,Q)); P via cvt_pk + ds_write_b64 into the wave-private
// XOR-swizzled Ps; PV A-read = contiguous ds_read_b128. Ps region is reused
// sequentially by the two q-tile passes (wave-private; DS ops in-order per
// wave; compiler fences). Output normalized in-register, staged via LDS.
// ---------------------------------------------------------------------------
#define KP 72
#define PMASK 1e-13f
__global__ __launch_bounds__(256, 2) void attn_fused(
    const unsigned short* __restrict__ q_buf,
    const unsigned short* __restrict__ k_buf,
    const unsigned short* __restrict__ vT_buf,
    const int* __restrict__ mask,
    unsigned short* __restrict__ attn_o) {
    __shared__ __align__(16) unsigned short Ks[64 * KP];
    __shared__ __align__(16) unsigned short Vs[64 * KP];
    __shared__ __align__(16) unsigned short Ps[4 * 16 * 64];  // per-wave swizzled P / O-stage
    __shared__ __align__(16) float Msf[64];

    // decode: xcd = j&7 pins bh group to XCD; p = pair index 0..15.
    const int j = blockIdx.x;            // 0..511
    const int xcd = j & 7;
    const int t = j >> 3;                // 0..63
    const int bhg = t & 3;
    const int p = t >> 2;                // 0..15
    const int bh = bhg * 8 + xcd;        // 0..31
    const int bb = bh >> 4, h = bh & 15;
    const int qa = 31 - p, qb = p;       // qa > qb always (p<=15)
    const int kta = qa + 1;              // staged tiles

    const int tid = threadIdx.x, wave = tid >> 6, lane = tid & 63;
    const int quad = lane >> 4, l16 = lane & 15;
    const unsigned short* qp = q_buf + (size_t)bh * SEQ * HD;
    const unsigned short* kp = k_buf + (size_t)bh * SEQ * HD;
    const unsigned short* vp = vT_buf + (size_t)bh * HD * SEQ;
    const int* mrow_ptr = mask + bb * SEQ;

    const int qrow_a = qa * 64 + wave * 16 + l16;
    const int qrow_b = qb * 64 + wave * 16 + l16;
    bf16x8 qfa[2], qfb[2];
    qfa[0] = *(const bf16x8*)(qp + (size_t)qrow_a * HD + 8 * quad);
    qfa[1] = *(const bf16x8*)(qp + (size_t)qrow_a * HD + 32 + 8 * quad);
    qfb[0] = *(const bf16x8*)(qp + (size_t)qrow_b * HD + 8 * quad);
    qfb[1] = *(const bf16x8*)(qp + (size_t)qrow_b * HD + 32 + 8 * quad);

    f32x4 oa[4] = {}, ob4[4] = {};
    float lsa = 0.0f, lsb = 0.0f;

    const int r0 = tid >> 3, c0 = (tid & 7) * 8;
    const int r1 = r0 + 32;

    // per-wave swizzled Ps addressing (bytes): row = q = l16, 128 B rows
    char* psb = (char*)Ps + wave * 2048 + l16 * 128;
    const int swz = (l16 & 7) << 4;

    // one q-tile pass over the staged tile kt (wave-uniform control)
    auto do_qtile = [&](const bf16x8* qf, f32x4* o, float& ls,
                        int qt_, int qrow_, int kt) {
        f32x4 sc[4];
        __builtin_amdgcn_s_setprio(1);
        #pragma unroll
        for (int ct = 0; ct < 4; ct++) {
            f32x4 z = {};
            #pragma unroll
            for (int ss = 0; ss < 2; ss++) {
                bf16x8 kf = *(const bf16x8*)&Ks[(16 * ct + l16) * KP + 32 * ss + 8 * quad];
                z = __builtin_amdgcn_mfma_f32_16x16x32_bf16(kf, qf[ss], z, 0, 0, 0);
            }
            sc[ct] = z;
        }
        __builtin_amdgcn_s_setprio(0);

        const bool diag = (kt == qt_);
        #pragma unroll
        for (int ct = 0; ct < 4; ct++) {
            float4 mq = *(const float4*)&Msf[16 * ct + 4 * quad];
            float mfs[4] = {mq.x, mq.y, mq.z, mq.w};
            const int kg0 = kt * 64 + 16 * ct + 4 * quad;
            float pv4[4];
            #pragma unroll
            for (int r = 0; r < 4; r++) {
                float pw = (mfs[r] != 0.0f) ? PMASK : exp2_fast(sc[ct][r]);
                if (diag && (kg0 + r) > qrow_) pw = 0.0f;
                ls += pw;
                pv4[r] = pw;
            }
            uint2 w;
            w.x = cvt_pk_bf16(pv4[0], pv4[1]);
            w.y = cvt_pk_bf16(pv4[2], pv4[3]);
            *(uint2*)(psb + ((quad * 8 + ct * 32) ^ swz)) = w;
        }
        asm volatile("" ::: "memory");   // order punned LDS write -> read

        __builtin_amdgcn_s_setprio(1);
        #pragma unroll
        for (int ss = 0; ss < 2; ss++) {
            bf16x8 pf = *(const bf16x8*)(psb + ((ss * 64 + quad * 16) ^ swz));
            #pragma unroll
            for (int dt = 0; dt < 4; dt++) {
                bf16x8 vf = *(const bf16x8*)&Vs[(16 * dt + l16) * KP + 32 * ss + 8 * quad];
                o[dt] = __builtin_amdgcn_mfma_f32_16x16x32_bf16(pf, vf, o[dt], 0, 0, 0);
            }
        }
        __builtin_amdgcn_s_setprio(0);
        asm volatile("" ::: "memory");   // order PV reads before next Ps overwrite
    };

    // prefetch tile 0; Msf holds 1.0 = masked, 0.0 = visible
    uint4 pk0, pk1, pv0, pv1; float pmv = 0.0f;
    pk0 = *(const uint4*)(kp + (size_t)r0 * HD + c0);
    pk1 = *(const uint4*)(kp + (size_t)r1 * HD + c0);
    pv0 = *(const uint4*)(vp + (size_t)r0 * SEQ + c0);
    pv1 = *(const uint4*)(vp + (size_t)r1 * SEQ + c0);
    if (tid < 64) pmv = mrow_ptr[tid] ? 1.0f : 0.0f;

    for (int kt = 0; kt < kta; kt++) {
        __syncthreads();
        *(uint4*)&Ks[r0 * KP + c0] = pk0;
        *(uint4*)&Ks[r1 * KP + c0] = pk1;
        *(uint4*)&Vs[r0 * KP + c0] = pv0;
        *(uint4*)&Vs[r1 * KP + c0] = pv1;
        if (tid < 64) Msf[tid] = pmv;
        if (kt + 1 < kta) {
            pk0 = *(const uint4*)(kp + (size_t)((kt + 1) * 64 + r0) * HD + c0);
            pk1 = *(const uint4*)(kp + (size_t)((kt + 1) * 64 + r1) * HD + c0);
            pv0 = *(const uint4*)(vp + (size_t)r0 * SEQ + (kt + 1) * 64 + c0);
            pv1 = *(const uint4*)(vp + (size_t)r1 * SEQ + (kt + 1) * 64 + c0);
            if (tid < 64) pmv = mrow_ptr[(kt + 1) * 64 + tid] ? 1.0f : 0.0f;
        }
        __syncthreads();

        do_qtile(qfa, oa, lsa, qa, qrow_a, kt);          // always
        if (kt <= qb)
            do_qtile(qfb, ob4, lsb, qb, qrow_b, kt);     // shared K/V tile
    }

    // normalize + store one q-tile's output (wave-private Ls staging)
    unsigned short* Ls = Ps + wave * 1024;   // 16 rows x 64 cols bf16 = 2 KB
    auto finish = [&](const f32x4* o, float ls, int qt_) {
        ls += __shfl_xor(ls, 16);
        ls += __shfl_xor(ls, 32);
        float linv[4];
        #pragma unroll
        for (int r = 0; r < 4; r++) linv[r] = 1.0f / __shfl(ls, quad * 4 + r);
        #pragma unroll
        for (int dt = 0; dt < 4; dt++)
            #pragma unroll
            for (int r = 0; r < 4; r++)
                Ls[(quad * 4 + r) * 64 + 16 * dt + l16] = f2bf(o[dt][r] * linv[r]);
        asm volatile("" ::: "memory");       // order punned LDS write -> read
        unsigned short* ob = attn_o + ((size_t)(bb * SEQ + qt_ * 64 + wave * 16)) * DIMC + h * HD;
        const int rlo = lane >> 3, dlo = (lane & 7) * 8;
        *(uint4*)(ob + (size_t)rlo * DIMC + dlo) = *(const uint4*)&Ls[lane * 8];
        *(uint4*)(ob + (size_t)(rlo + 8) * DIMC + dlo) = *(const uint4*)&Ls[512 + lane * 8];
        asm volatile("" ::: "memory");       // order reads before next reuse
    };
    finish(oa, lsa, qa);
    finish(ob4, lsb, qb);
}

// ---------------------------------------------------------------------------
extern "C" void kernel_launch(void* const* d_in, const int* in_sizes, int n_in,
                              void* d_out, int out_size, void* d_ws, size_t ws_size,
                              hipStream_t stream) {
    const float* x     = (const float*)d_in[0];
    const int*   mask  = (const int*)d_in[1];
    const float* ln1w  = (const float*)d_in[2];
    const float* ln1b  = (const float*)d_in[3];
    const float* qkvw  = (const float*)d_in[4];
    const float* projw = (const float*)d_in[5];
    const float* projb = (const float*)d_in[6];
    const float* ln2w  = (const float*)d_in[7];
    const float* ln2b  = (const float*)d_in[8];
    const float* fc1w  = (const float*)d_in[9];
    const float* fc1b  = (const float*)d_in[10];
    const float* fc2w  = (const float*)d_in[11];
    const float* fc2b  = (const float*)d_in[12];

    // Workspace (80 MB, lifetime reuse):
    //  [0,6M)    qkv_wT (dead after QKV gemm)
    //  [6,8M)    proj_wT
    //  [8,16M)   fc1_wT
    //  [16,24M)  fc2_wT
    //  [24,32M)  ln_buf (ln1, later ln2)
    //  [32,40M)  q_buf   | h_buf [32,64M) at FC1
    //  [40,48M)  k_buf
    //  [48,56M)  attn_o (fused attention output)
    //  [56,64M)  vT_buf (written directly by QKV, transposed)
    //  [64,80M)  x1 fp32
    char* base = (char*)d_ws;
    unsigned short* qkv_wT  = (unsigned short*)(base);
    unsigned short* proj_wT = (unsigned short*)(base + (size_t)6  * 1024 * 1024);
    unsigned short* fc1_wT  = (unsigned short*)(base + (size_t)8  * 1024 * 1024);
    unsigned short* fc2_wT  = (unsigned short*)(base + (size_t)16 * 1024 * 1024);
    unsigned short* ln_buf  = (unsigned short*)(base + (size_t)24 * 1024 * 1024);
    unsigned short* q_buf   = (unsigned short*)(base + (size_t)32 * 1024 * 1024);
    unsigned short* k_buf   = (unsigned short*)(base + (size_t)40 * 1024 * 1024);
    unsigned short* attn_o  = (unsigned short*)(base + (size_t)48 * 1024 * 1024);
    unsigned short* vT_buf  = (unsigned short*)(base + (size_t)56 * 1024 * 1024);
    unsigned short* h_buf   = (unsigned short*)(base + (size_t)32 * 1024 * 1024); // reuse
    float*          x1      = (float*)(base + (size_t)64 * 1024 * 1024);

    // 1. all 4 weight transposes in one launch
    fused_transpose<<<3072, 256, 0, stream>>>(qkvw, projw, fc1w, fc2w,
                                              qkv_wT, proj_wT, fc1_wT, fc2_wT);

    // 2. LN1 (fp32 x -> bf16)
    ln_kernel<<<MTOK, 256, 0, stream>>>(x, ln1w, ln1b, ln_buf);

    // 3. QKV GEMM -> q (pre-scaled by log2e/8), k [bh][t][d]; V DIRECTLY
    //    transposed into vT_buf [bh][d][t] (packed 8B stores).
    gemm_kernel<EP_QKV, 3072, 1024, 128, 128, 64><<<dim3(24, 32), 256, 0, stream>>>(
        ln_buf, qkv_wT, nullptr, nullptr, nullptr, q_buf, k_buf, vT_buf);

    // 4. fused attention, complementary-pair balanced (512 blocks: one per
    //    (pair, bh), 33 compute-units each, bh pinned to XCD) -> attn_o
    attn_fused<<<512, 256, 0, stream>>>(q_buf, k_buf, vT_buf, mask, attn_o);

    // 5. proj GEMM + residual(x fp32) -> x1
    gemm_kernel<EP_PROJ, 1024, 1024, 64, 64, 64><<<1024, 256, 0, stream>>>(
        attn_o, proj_wT, projb, x, x1, nullptr, nullptr, nullptr);

    // 6. LN2 (fp32 x1 -> bf16)
    ln_kernel<<<MTOK, 256, 0, stream>>>(x1, ln2w, ln2b, ln_buf);

    // 7. FC1 + GELU -> h_buf (bf16)
    gemm_kernel<EP_FC1, 4096, 1024, 128, 128, 64><<<dim3(32, 32), 256, 0, stream>>>(
        ln_buf, fc1_wT, fc1b, nullptr, h_buf, nullptr, nullptr, nullptr);

    // 8. FC2 + residual(x1) -> d_out
    gemm_kernel<EP_FC2, 1024, 4096, 64, 64, 64><<<1024, 256, 0, stream>>>(
        h_buf, fc2_wT, fc2b, x1, d_out, nullptr, nullptr, nullptr);
}

// Round 9
// 340.835 us; speedup vs baseline: 1.0724x; 1.0146x over previous
//
#include <hip/hip_runtime.h>
#include <stdint.h>

#define DIMC 1024
#define HEADS 16
#define HD 64
#define HIDDENC 4096
#define BATCH 2
#define SEQ 2048
#define MTOK (BATCH*SEQ)

typedef __bf16 bf16x8 __attribute__((ext_vector_type(8)));
typedef float f32x4 __attribute__((ext_vector_type(4)));

__device__ __forceinline__ float bf2f(unsigned short u) {
    union { unsigned int u; float f; } v; v.u = ((unsigned int)u) << 16; return v.f;
}
__device__ __forceinline__ unsigned short f2bf(float f) {
    union { float f; unsigned int u; } v; v.f = f;
    unsigned int r = v.u + 0x7fffu + ((v.u >> 16) & 1u);
    return (unsigned short)(r >> 16);
}
// pack 2 f32 -> 2 bf16 (RNE), src0 -> low half (T12 recipe, guide-verified)
__device__ __forceinline__ unsigned int cvt_pk_bf16(float lo, float hi) {
    unsigned int r;
    asm("v_cvt_pk_bf16_f32 %0, %1, %2" : "=v"(r) : "v"(lo), "v"(hi));
    return r;
}
// 2^x (log2e is pre-folded into the Q scale)
__device__ __forceinline__ float exp2_fast(float x) {
#if __has_builtin(__builtin_amdgcn_exp2f)
    return __builtin_amdgcn_exp2f(x);
#else
    float r;
    asm("v_exp_f32 %0, %1" : "=v"(r) : "v"(x));
    return r;
#endif
}

#define GLOAD_LDS(g, l) \
    __builtin_amdgcn_global_load_lds( \
        (const __attribute__((address_space(1))) void*)(g), \
        (__attribute__((address_space(3))) void*)(l), 16, 0, 0)

// ---------------------------------------------------------------------------
// Fused weight transposes: fp32 (K x N) -> bf16 (N x K) for all 4 weights.
// ---------------------------------------------------------------------------
__device__ __forceinline__ void tp_tile(const float* __restrict__ in,
                                        unsigned short* __restrict__ out,
                                        int K, int N, int tn, int tk, int tid,
                                        unsigned short (*tile)[65]) {
    for (int c = tid; c < 1024; c += 256) {
        int r = c >> 4, coff = (c & 15) * 4;
        float4 v = *(const float4*)(in + (size_t)(tk + r) * N + tn + coff);
        tile[r][coff + 0] = f2bf(v.x);
        tile[r][coff + 1] = f2bf(v.y);
        tile[r][coff + 2] = f2bf(v.z);
        tile[r][coff + 3] = f2bf(v.w);
    }
    __syncthreads();
    for (int c = tid; c < 512; c += 256) {
        int rn = c >> 3, off = (c & 7) * 8;
        unsigned short tmp[8];
        #pragma unroll
        for (int j = 0; j < 8; j++) tmp[j] = tile[off + j][rn];
        *(uint4*)(out + (size_t)(tn + rn) * K + tk + off) = *(uint4*)tmp;
    }
}

__global__ __launch_bounds__(256) void fused_transpose(
    const float* __restrict__ qkvw, const float* __restrict__ projw,
    const float* __restrict__ fc1w, const float* __restrict__ fc2w,
    unsigned short* __restrict__ qkv_wT, unsigned short* __restrict__ proj_wT,
    unsigned short* __restrict__ fc1_wT, unsigned short* __restrict__ fc2_wT) {
    __shared__ unsigned short tile[64][65];
    int id = blockIdx.x, tid = threadIdx.x;
    if (id < 768) {
        tp_tile(qkvw, qkv_wT, 1024, 3072, (id % 48) * 64, (id / 48) * 64, tid, tile);
    } else if (id < 1024) {
        id -= 768;
        tp_tile(projw, proj_wT, 1024, 1024, (id % 16) * 64, (id / 16) * 64, tid, tile);
    } else if (id < 2048) {
        id -= 1024;
        tp_tile(fc1w, fc1_wT, 1024, 4096, (id % 64) * 64, (id / 64) * 64, tid, tile);
    } else {
        id -= 2048;
        tp_tile(fc2w, fc2_wT, 4096, 1024, (id % 16) * 64, (id / 16) * 64, tid, tile);
    }
}

// ---------------------------------------------------------------------------
// LayerNorm: f32 input, f32 w/b, bf16 output. One block per row (DIMC=1024).
// ---------------------------------------------------------------------------
__global__ __launch_bounds__(256) void ln_kernel(const float* __restrict__ inp,
                                                 const float* __restrict__ w,
                                                 const float* __restrict__ b,
                                                 unsigned short* __restrict__ out) {
    int row = blockIdx.x;
    int tid = threadIdx.x;
    int base = tid * 4;
    float4 v = *(const float4*)(inp + (size_t)row * DIMC + base);
    float x[4] = {v.x, v.y, v.z, v.w};
    float s1 = x[0] + x[1] + x[2] + x[3];
    float s2 = x[0]*x[0] + x[1]*x[1] + x[2]*x[2] + x[3]*x[3];
    #pragma unroll
    for (int off = 32; off > 0; off >>= 1) {
        s1 += __shfl_xor(s1, off);
        s2 += __shfl_xor(s2, off);
    }
    __shared__ float red[8];
    int wv = tid >> 6;
    if ((tid & 63) == 0) { red[wv] = s1; red[4 + wv] = s2; }
    __syncthreads();
    s1 = red[0] + red[1] + red[2] + red[3];
    s2 = red[4] + red[5] + red[6] + red[7];
    float mean = s1 * (1.0f / DIMC);
    float var  = s2 * (1.0f / DIMC) - mean * mean;
    float rstd = rsqrtf(var + 1e-5f);
    float4 wv4 = *(const float4*)(w + base);
    float4 bv4 = *(const float4*)(b + base);
    ushort4 o;
    o.x = f2bf((x[0] - mean) * rstd * wv4.x + bv4.x);
    o.y = f2bf((x[1] - mean) * rstd * wv4.y + bv4.y);
    o.z = f2bf((x[2] - mean) * rstd * wv4.z + bv4.z);
    o.w = f2bf((x[3] - mean) * rstd * wv4.w + bv4.w);
    *(ushort4*)(out + (size_t)row * DIMC + base) = o;
}

// ---------------------------------------------------------------------------
// bf16 MFMA GEMM: C(M x N) = A(M x K) @ BT(N x K)^T.
// Tile TM x TN, 4 waves (2x2), XOR-swizzled LDS, global_load_lds staging,
// double-buffered with counted vmcnt (R4).
//
// Mapping (A/B-measured):
//  - QKV (128x128), FC1 (128x64 as of R9): 2D dim3 grid (R4 mapping). R5
//    rectangle REGRESSED FC1 (lockstep A-panel reads); dim3 spreads
//    co-resident blocks over different m-rows. FC1 TN=64: 2048 blocks,
//    LDS 48KB -> 3 blocks/CU (R8 FC1 was 2/CU grid-limited).
//  - PROJ/FC2 (64x64): 1D XCD rectangle (MG=4 x NG=2). R4 evidence: naive
//    dim3 put each m-tile's n-blocks on all 8 XCDs -> A-dup=8, FETCH 143MB.
// ---------------------------------------------------------------------------
enum { EP_QKV = 0, EP_PROJ = 1, EP_FC1 = 2, EP_FC2 = 3 };

template <int MODE, int N, int K, int TM, int TN, int BK>
__global__ __launch_bounds__(256) void gemm_kernel(
    const unsigned short* __restrict__ A,
    const unsigned short* __restrict__ BT,
    const float* __restrict__ bias,
    const float* __restrict__ res,      // fp32 residual (PROJ: x, FC2: x1)
    void* __restrict__ out0,
    unsigned short* __restrict__ q_buf,
    unsigned short* __restrict__ k_buf,
    unsigned short* __restrict__ v_buf) {  // QKV: vT_buf [bh][d][t]
    constexpr int MI = TM / 32;          // m-fragments per wave (2 waves in m)
    constexpr int NJ = TN / 32;          // n-fragments per wave (2 waves in n)
    constexpr int CPR = BK / 8;
    constexpr int NT = K / BK;
    constexpr int N_LD = (TM + TN) * BK / 2048;  // gload_lds per thread per tile
    static_assert(N_LD == 8 || N_LD == 6 || N_LD == 4, "vmcnt literal");
    constexpr int NX = N / TN;
    constexpr int NY = MTOK / TM;
    constexpr int MG = 4, NG = 2;        // XCD rectangle partition (PROJ/FC2)
    constexpr int NXG = NX / NG, NYG = NY / MG;

    __shared__ __align__(16) unsigned short As[2 * TM * BK];
    __shared__ __align__(16) unsigned short Bs[2 * TN * BK];
    const int tid = threadIdx.x;

    int m0, n0;
    if constexpr (MODE == EP_PROJ || MODE == EP_FC2) {
        // 1D grid, consecutive ids round-robin XCDs -> rectangle per XCD
        const int jb = blockIdx.x;
        const int xcd = jb & 7;
        const int tb = jb >> 3;
        const int mg = xcd >> 1, ng = xcd & 1;
        m0 = (mg * NYG + tb / NXG) * TM;
        n0 = (ng * NXG + tb % NXG) * TN;
    } else {
        m0 = blockIdx.y * TM;
        n0 = blockIdx.x * TN;
    }

    const int wave = tid >> 6, lane = tid & 63;
    const int wm = wave >> 1, wn = wave & 1;
    const int quad = lane >> 4, l16 = lane & 15;
    const int swz = l16 & (CPR - 1);

    f32x4 acc[MI][NJ] = {};

    auto stage = [&](int t, int b) {
        const size_t kk = (size_t)t * BK;
        #pragma unroll
        for (int it = 0; it < TM * BK / 2048; ++it) {
            int c = tid + 256 * it;
            int row = c / CPR, jj = c % CPR;
            int col8 = (jj ^ (row & (CPR - 1))) * 8;
            GLOAD_LDS(A + (size_t)(m0 + row) * K + kk + col8,
                      As + (size_t)b * TM * BK + (size_t)c * 8);
        }
        #pragma unroll
        for (int it = 0; it < TN * BK / 2048; ++it) {
            int c = tid + 256 * it;
            int row = c / CPR, jj = c % CPR;
            int col8 = (jj ^ (row & (CPR - 1))) * 8;
            GLOAD_LDS(BT + (size_t)(n0 + row) * K + kk + col8,
                      Bs + (size_t)b * TN * BK + (size_t)c * 8);
        }
    };

    stage(0, 0);
    for (int t = 0; t < NT; ++t) {
        const int cur = t & 1;
        if (t + 1 < NT) {
            stage(t + 1, cur ^ 1);
            // wait tile t's N_LD loads; leave tile t+1's in flight (never 0)
            if constexpr (N_LD == 8)      asm volatile("s_waitcnt vmcnt(8)" ::: "memory");
            else if constexpr (N_LD == 6) asm volatile("s_waitcnt vmcnt(6)" ::: "memory");
            else                          asm volatile("s_waitcnt vmcnt(4)" ::: "memory");
        } else {
            asm volatile("s_waitcnt vmcnt(0)" ::: "memory");
        }
        __builtin_amdgcn_s_barrier();

        const unsigned short* Asb = As + (size_t)cur * TM * BK;
        const unsigned short* Bsb = Bs + (size_t)cur * TN * BK;
        #pragma unroll
        for (int kk2 = 0; kk2 < BK / 32; ++kk2) {
            bf16x8 af[MI], bfv[NJ];
            #pragma unroll
            for (int i = 0; i < MI; i++) {
                int row = 16 * MI * wm + 16 * i + l16;
                int sj = (4 * kk2 + quad) ^ swz;
                af[i] = *(const bf16x8*)&Asb[row * BK + sj * 8];
            }
            #pragma unroll
            for (int j = 0; j < NJ; j++) {
                int row = 16 * NJ * wn + 16 * j + l16;
                int sj = (4 * kk2 + quad) ^ swz;
                bfv[j] = *(const bf16x8*)&Bsb[row * BK + sj * 8];
            }
            #pragma unroll
            for (int i = 0; i < MI; i++)
                #pragma unroll
                for (int j = 0; j < NJ; j++)
                    acc[i][j] = __builtin_amdgcn_mfma_f32_16x16x32_bf16(af[i], bfv[j], acc[i][j], 0, 0, 0);
        }
        // all this wave's ds_reads complete (results consumed), then barrier so
        // next iter's stage into buf[cur] can't race other waves' reads.
        asm volatile("s_waitcnt lgkmcnt(0)" ::: "memory");
        __builtin_amdgcn_s_barrier();
    }

    #pragma unroll
    for (int i = 0; i < MI; i++) {
        #pragma unroll
        for (int j = 0; j < NJ; j++) {
            int nl = n0 + 16 * NJ * wn + 16 * j + l16;
            if (MODE == EP_QKV) {
                int which = nl >> 10, rem = nl & 1023;
                int hh = rem >> 6, d = rem & 63;
                int ml0 = m0 + 16 * MI * wm + 16 * i + quad * 4;  // r=0..3 -> t0..t0+3
                int bb2 = ml0 >> 11, t0 = ml0 & 2047;
                int bh = bb2 * HEADS + hh;
                if (which == 2) {
                    // V written TRANSPOSED [bh][d][t]: 4 consecutive t -> one 8B store
                    uint2 w;
                    w.x = cvt_pk_bf16(acc[i][j][0], acc[i][j][1]);
                    w.y = cvt_pk_bf16(acc[i][j][2], acc[i][j][3]);
                    *(uint2*)(v_buf + ((size_t)bh * HD + d) * SEQ + t0) = w;
                } else if (which == 0) {
                    // q pre-scale = (1/8)*log2(e) so softmax is a bare v_exp_f32 (2^x)
                    #pragma unroll
                    for (int r = 0; r < 4; r++)
                        q_buf[((size_t)bh * SEQ + t0 + r) * HD + d] =
                            f2bf(acc[i][j][r] * 0.18033688011112042f);
                } else {
                    #pragma unroll
                    for (int r = 0; r < 4; r++)
                        k_buf[((size_t)bh * SEQ + t0 + r) * HD + d] = f2bf(acc[i][j][r]);
                }
            } else {
                float bval = bias[nl];
                #pragma unroll
                for (int r = 0; r < 4; r++) {
                    int ml = m0 + 16 * MI * wm + 16 * i + quad * 4 + r;
                    float v = acc[i][j][r];
                    if (MODE == EP_PROJ) {
                        float* x1 = (float*)out0;
                        x1[(size_t)ml * DIMC + nl] = res[(size_t)ml * DIMC + nl] + v + bval;
                    } else if (MODE == EP_FC1) {
                        float g = v + bval;
                        float u = 1.5957691216f * (g + 0.044715f * g * g * g);
                        float gv = g / (1.0f + __expf(-u));
                        ((unsigned short*)out0)[(size_t)ml * HIDDENC + nl] = f2bf(gv);
                    } else {
                        ((float*)out0)[(size_t)ml * DIMC + nl] =
                            res[(size_t)ml * DIMC + nl] + v + bval;
                    }
                }
            }
        }
    }
}

// ---------------------------------------------------------------------------
// FUSED causal flash attention, complementary-pair balanced (R8) +
// PAIR-INTERLEAVED shared range (R9).
// One block per (pair p, bh): q-tiles qa=31-p, qb=p; 33 units/block uniform.
// R9: for kt <= qb both q-tiles are processed in ONE pass with SHARED kf/vf
// loads (each Ks/Vs fragment read once, two MFMAs) and DUAL Ps buffers, so
// SM_a's VALU overlaps b's MFMAs (separate pipes; independent chains).
// R8 evidence: MfmaUtil 11.6 / VALU 29.5 / occ 18% at optimal traffic ->
// intra-block latency chain is the limiter.
//
// Key-padding: masked keys get CONSTANT 1e-13 (uniform when row fully
// masked, matching ref fp32 +(-1e9)). Causal diag in shared range applies
// only to tile b (kt <= qb < qa). Swapped QK^T; P via cvt_pk+ds_write_b64
// into wave-private XOR-swizzled Ps; PV A-read = contiguous ds_read_b128.
// Output normalized in-register, staged via LDS for coalesced stores.
// ---------------------------------------------------------------------------
#define KP 72
#define PMASK 1e-13f
__global__ __launch_bounds__(256, 2) void attn_fused(
    const unsigned short* __restrict__ q_buf,
    const unsigned short* __restrict__ k_buf,
    const unsigned short* __restrict__ vT_buf,
    const int* __restrict__ mask,
    unsigned short* __restrict__ attn_o) {
    __shared__ __align__(16) unsigned short Ks[64 * KP];
    __shared__ __align__(16) unsigned short Vs[64 * KP];
    __shared__ __align__(16) unsigned short PsA[4 * 16 * 64]; // per-wave swizzled P (tile a) / O-stage
    __shared__ __align__(16) unsigned short PsB[4 * 16 * 64]; // per-wave swizzled P (tile b)
    __shared__ __align__(16) float Msf[64];

    // decode: xcd = j&7 pins bh group to XCD; p = pair index 0..15.
    const int j = blockIdx.x;            // 0..511
    const int xcd = j & 7;
    const int t = j >> 3;                // 0..63
    const int bhg = t & 3;
    const int p = t >> 2;                // 0..15
    const int bh = bhg * 8 + xcd;        // 0..31
    const int bb = bh >> 4, h = bh & 15;
    const int qa = 31 - p, qb = p;       // qa > qb always (p<=15)
    const int kta = qa + 1;              // staged tiles

    const int tid = threadIdx.x, wave = tid >> 6, lane = tid & 63;
    const int quad = lane >> 4, l16 = lane & 15;
    const unsigned short* qp = q_buf + (size_t)bh * SEQ * HD;
    const unsigned short* kp = k_buf + (size_t)bh * SEQ * HD;
    const unsigned short* vp = vT_buf + (size_t)bh * HD * SEQ;
    const int* mrow_ptr = mask + bb * SEQ;

    const int qrow_a = qa * 64 + wave * 16 + l16;
    const int qrow_b = qb * 64 + wave * 16 + l16;
    bf16x8 qfa[2], qfb[2];
    qfa[0] = *(const bf16x8*)(qp + (size_t)qrow_a * HD + 8 * quad);
    qfa[1] = *(const bf16x8*)(qp + (size_t)qrow_a * HD + 32 + 8 * quad);
    qfb[0] = *(const bf16x8*)(qp + (size_t)qrow_b * HD + 8 * quad);
    qfb[1] = *(const bf16x8*)(qp + (size_t)qrow_b * HD + 32 + 8 * quad);

    f32x4 oa[4] = {}, ob4[4] = {};
    float lsa = 0.0f, lsb = 0.0f;

    const int r0 = tid >> 3, c0 = (tid & 7) * 8;
    const int r1 = r0 + 32;

    // per-wave swizzled Ps addressing (bytes): row = q = l16, 128 B rows
    char* psA = (char*)PsA + wave * 2048 + l16 * 128;
    char* psB = (char*)PsB + wave * 2048 + l16 * 128;
    const int swz = (l16 & 7) << 4;

    // solo pass (tile a only; used for kt > qb)
    auto solo_pass = [&](int kt) {
        f32x4 sc[4];
        __builtin_amdgcn_s_setprio(1);
        #pragma unroll
        for (int ct = 0; ct < 4; ct++) {
            f32x4 z = {};
            #pragma unroll
            for (int ss = 0; ss < 2; ss++) {
                bf16x8 kf = *(const bf16x8*)&Ks[(16 * ct + l16) * KP + 32 * ss + 8 * quad];
                z = __builtin_amdgcn_mfma_f32_16x16x32_bf16(kf, qfa[ss], z, 0, 0, 0);
            }
            sc[ct] = z;
        }
        __builtin_amdgcn_s_setprio(0);

        const bool diag = (kt == qa);
        #pragma unroll
        for (int ct = 0; ct < 4; ct++) {
            float4 mq = *(const float4*)&Msf[16 * ct + 4 * quad];
            float mfs[4] = {mq.x, mq.y, mq.z, mq.w};
            const int kg0 = kt * 64 + 16 * ct + 4 * quad;
            float pv4[4];
            #pragma unroll
            for (int r = 0; r < 4; r++) {
                float pw = (mfs[r] != 0.0f) ? PMASK : exp2_fast(sc[ct][r]);
                if (diag && (kg0 + r) > qrow_a) pw = 0.0f;
                lsa += pw;
                pv4[r] = pw;
            }
            uint2 w;
            w.x = cvt_pk_bf16(pv4[0], pv4[1]);
            w.y = cvt_pk_bf16(pv4[2], pv4[3]);
            *(uint2*)(psA + ((quad * 8 + ct * 32) ^ swz)) = w;
        }
        asm volatile("" ::: "memory");   // order punned LDS write -> read

        __builtin_amdgcn_s_setprio(1);
        #pragma unroll
        for (int ss = 0; ss < 2; ss++) {
            bf16x8 pf = *(const bf16x8*)(psA + ((ss * 64 + quad * 16) ^ swz));
            #pragma unroll
            for (int dt = 0; dt < 4; dt++) {
                bf16x8 vf = *(const bf16x8*)&Vs[(16 * dt + l16) * KP + 32 * ss + 8 * quad];
                oa[dt] = __builtin_amdgcn_mfma_f32_16x16x32_bf16(pf, vf, oa[dt], 0, 0, 0);
            }
        }
        __builtin_amdgcn_s_setprio(0);
        asm volatile("" ::: "memory");   // order PV reads before next Ps overwrite
    };

    // pair pass (kt <= qb): shared kf/vf loads, dual chains, dual Ps.
    auto pair_pass = [&](int kt) {
        f32x4 sa[4], sb[4];
        __builtin_amdgcn_s_setprio(1);
        #pragma unroll
        for (int ct = 0; ct < 4; ct++) {
            f32x4 za = {}, zb = {};
            #pragma unroll
            for (int ss = 0; ss < 2; ss++) {
                bf16x8 kf = *(const bf16x8*)&Ks[(16 * ct + l16) * KP + 32 * ss + 8 * quad];
                za = __builtin_amdgcn_mfma_f32_16x16x32_bf16(kf, qfa[ss], za, 0, 0, 0);
                zb = __builtin_amdgcn_mfma_f32_16x16x32_bf16(kf, qfb[ss], zb, 0, 0, 0);
            }
            sa[ct] = za; sb[ct] = zb;
        }
        __builtin_amdgcn_s_setprio(0);

        const bool diag_b = (kt == qb);  // diag for a impossible here (kt<=qb<qa)
        #pragma unroll
        for (int ct = 0; ct < 4; ct++) {
            float4 mq = *(const float4*)&Msf[16 * ct + 4 * quad];
            float mfs[4] = {mq.x, mq.y, mq.z, mq.w};
            const int kg0 = kt * 64 + 16 * ct + 4 * quad;
            float pa4[4], pb4[4];
            #pragma unroll
            for (int r = 0; r < 4; r++) {
                float pa = (mfs[r] != 0.0f) ? PMASK : exp2_fast(sa[ct][r]);
                float pb = (mfs[r] != 0.0f) ? PMASK : exp2_fast(sb[ct][r]);
                if (diag_b && (kg0 + r) > qrow_b) pb = 0.0f;
                lsa += pa; lsb += pb;
                pa4[r] = pa; pb4[r] = pb;
            }
            uint2 wa, wb;
            wa.x = cvt_pk_bf16(pa4[0], pa4[1]);
            wa.y = cvt_pk_bf16(pa4[2], pa4[3]);
            wb.x = cvt_pk_bf16(pb4[0], pb4[1]);
            wb.y = cvt_pk_bf16(pb4[2], pb4[3]);
            *(uint2*)(psA + ((quad * 8 + ct * 32) ^ swz)) = wa;
            *(uint2*)(psB + ((quad * 8 + ct * 32) ^ swz)) = wb;
        }
        asm volatile("" ::: "memory");   // order punned LDS write -> read

        __builtin_amdgcn_s_setprio(1);
        #pragma unroll
        for (int ss = 0; ss < 2; ss++) {
            bf16x8 pfa = *(const bf16x8*)(psA + ((ss * 64 + quad * 16) ^ swz));
            bf16x8 pfb = *(const bf16x8*)(psB + ((ss * 64 + quad * 16) ^ swz));
            #pragma unroll
            for (int dt = 0; dt < 4; dt++) {
                bf16x8 vf = *(const bf16x8*)&Vs[(16 * dt + l16) * KP + 32 * ss + 8 * quad];
                oa[dt]  = __builtin_amdgcn_mfma_f32_16x16x32_bf16(pfa, vf, oa[dt], 0, 0, 0);
                ob4[dt] = __builtin_amdgcn_mfma_f32_16x16x32_bf16(pfb, vf, ob4[dt], 0, 0, 0);
            }
        }
        __builtin_amdgcn_s_setprio(0);
        asm volatile("" ::: "memory");   // order PV reads before next Ps overwrite
    };

    // prefetch tile 0; Msf holds 1.0 = masked, 0.0 = visible
    uint4 pk0, pk1, pv0, pv1; float pmv = 0.0f;
    pk0 = *(const uint4*)(kp + (size_t)r0 * HD + c0);
    pk1 = *(const uint4*)(kp + (size_t)r1 * HD + c0);
    pv0 = *(const uint4*)(vp + (size_t)r0 * SEQ + c0);
    pv1 = *(const uint4*)(vp + (size_t)r1 * SEQ + c0);
    if (tid < 64) pmv = mrow_ptr[tid] ? 1.0f : 0.0f;

    for (int kt = 0; kt < kta; kt++) {
        __syncthreads();
        *(uint4*)&Ks[r0 * KP + c0] = pk0;
        *(uint4*)&Ks[r1 * KP + c0] = pk1;
        *(uint4*)&Vs[r0 * KP + c0] = pv0;
        *(uint4*)&Vs[r1 * KP + c0] = pv1;
        if (tid < 64) Msf[tid] = pmv;
        if (kt + 1 < kta) {
            pk0 = *(const uint4*)(kp + (size_t)((kt + 1) * 64 + r0) * HD + c0);
            pk1 = *(const uint4*)(kp + (size_t)((kt + 1) * 64 + r1) * HD + c0);
            pv0 = *(const uint4*)(vp + (size_t)r0 * SEQ + (kt + 1) * 64 + c0);
            pv1 = *(const uint4*)(vp + (size_t)r1 * SEQ + (kt + 1) * 64 + c0);
            if (tid < 64) pmv = mrow_ptr[(kt + 1) * 64 + tid] ? 1.0f : 0.0f;
        }
        __syncthreads();

        if (kt <= qb) pair_pass(kt);
        else          solo_pass(kt);
    }

    // normalize + store one q-tile's output (wave-private Ls staging in PsA)
    unsigned short* Ls = PsA + wave * 1024;  // 16 rows x 64 cols bf16 = 2 KB
    auto finish = [&](const f32x4* o, float ls, int qt_) {
        ls += __shfl_xor(ls, 16);
        ls += __shfl_xor(ls, 32);
        float linv[4];
        #pragma unroll
        for (int r = 0; r < 4; r++) linv[r] = 1.0f / __shfl(ls, quad * 4 + r);
        #pragma unroll
        for (int dt = 0; dt < 4; dt++)
            #pragma unroll
            for (int r = 0; r < 4; r++)
                Ls[(quad * 4 + r) * 64 + 16 * dt + l16] = f2bf(o[dt][r] * linv[r]);
        asm volatile("" ::: "memory");       // order punned LDS write -> read
        unsigned short* ob = attn_o + ((size_t)(bb * SEQ + qt_ * 64 + wave * 16)) * DIMC + h * HD;
        const int rlo = lane >> 3, dlo = (lane & 7) * 8;
        *(uint4*)(ob + (size_t)rlo * DIMC + dlo) = *(const uint4*)&Ls[lane * 8];
        *(uint4*)(ob + (size_t)(rlo + 8) * DIMC + dlo) = *(const uint4*)&Ls[512 + lane * 8];
        asm volatile("" ::: "memory");       // order reads before next reuse
    };
    finish(oa, lsa, qa);
    finish(ob4, lsb, qb);
}

// ---------------------------------------------------------------------------
extern "C" void kernel_launch(void* const* d_in, const int* in_sizes, int n_in,
                              void* d_out, int out_size, void* d_ws, size_t ws_size,
                              hipStream_t stream) {
    const float* x     = (const float*)d_in[0];
    const int*   mask  = (const int*)d_in[1];
    const float* ln1w  = (const float*)d_in[2];
    const float* ln1b  = (const float*)d_in[3];
    const float* qkvw  = (const float*)d_in[4];
    const float* projw = (const float*)d_in[5];
    const float* projb = (const float*)d_in[6];
    const float* ln2w  = (const float*)d_in[7];
    const float* ln2b  = (const float*)d_in[8];
    const float* fc1w  = (const float*)d_in[9];
    const float* fc1b  = (const float*)d_in[10];
    const float* fc2w  = (const float*)d_in[11];
    const float* fc2b  = (const float*)d_in[12];

    // Workspace (80 MB, lifetime reuse):
    //  [0,6M)    qkv_wT (dead after QKV gemm)
    //  [6,8M)    proj_wT
    //  [8,16M)   fc1_wT
    //  [16,24M)  fc2_wT
    //  [24,32M)  ln_buf (ln1, later ln2)
    //  [32,40M)  q_buf   | h_buf [32,64M) at FC1
    //  [40,48M)  k_buf
    //  [48,56M)  attn_o (fused attention output)
    //  [56,64M)  vT_buf (written directly by QKV, transposed)
    //  [64,80M)  x1 fp32
    char* base = (char*)d_ws;
    unsigned short* qkv_wT  = (unsigned short*)(base);
    unsigned short* proj_wT = (unsigned short*)(base + (size_t)6  * 1024 * 1024);
    unsigned short* fc1_wT  = (unsigned short*)(base + (size_t)8  * 1024 * 1024);
    unsigned short* fc2_wT  = (unsigned short*)(base + (size_t)16 * 1024 * 1024);
    unsigned short* ln_buf  = (unsigned short*)(base + (size_t)24 * 1024 * 1024);
    unsigned short* q_buf   = (unsigned short*)(base + (size_t)32 * 1024 * 1024);
    unsigned short* k_buf   = (unsigned short*)(base + (size_t)40 * 1024 * 1024);
    unsigned short* attn_o  = (unsigned short*)(base + (size_t)48 * 1024 * 1024);
    unsigned short* vT_buf  = (unsigned short*)(base + (size_t)56 * 1024 * 1024);
    unsigned short* h_buf   = (unsigned short*)(base + (size_t)32 * 1024 * 1024); // reuse
    float*          x1      = (float*)(base + (size_t)64 * 1024 * 1024);

    // 1. all 4 weight transposes in one launch
    fused_transpose<<<3072, 256, 0, stream>>>(qkvw, projw, fc1w, fc2w,
                                              qkv_wT, proj_wT, fc1_wT, fc2_wT);

    // 2. LN1 (fp32 x -> bf16)
    ln_kernel<<<MTOK, 256, 0, stream>>>(x, ln1w, ln1b, ln_buf);

    // 3. QKV GEMM -> q (pre-scaled by log2e/8), k [bh][t][d]; V DIRECTLY
    //    transposed into vT_buf [bh][d][t] (packed 8B stores).
    gemm_kernel<EP_QKV, 3072, 1024, 128, 128, 64><<<dim3(24, 32), 256, 0, stream>>>(
        ln_buf, qkv_wT, nullptr, nullptr, nullptr, q_buf, k_buf, vT_buf);

    // 4. fused attention, pair-balanced + pair-interleaved (512 blocks) -> attn_o
    attn_fused<<<512, 256, 0, stream>>>(q_buf, k_buf, vT_buf, mask, attn_o);

    // 5. proj GEMM + residual(x fp32) -> x1
    gemm_kernel<EP_PROJ, 1024, 1024, 64, 64, 64><<<1024, 256, 0, stream>>>(
        attn_o, proj_wT, projb, x, x1, nullptr, nullptr, nullptr);

    // 6. LN2 (fp32 x1 -> bf16)
    ln_kernel<<<MTOK, 256, 0, stream>>>(x1, ln2w, ln2b, ln_buf);

    // 7. FC1 + GELU -> h_buf (bf16); R9: TN=64, 2048 blocks, 48KB LDS -> 3/CU
    gemm_kernel<EP_FC1, 4096, 1024, 128, 64, 64><<<dim3(64, 32), 256, 0, stream>>>(
        ln_buf, fc1_wT, fc1b, nullptr, h_buf, nullptr, nullptr, nullptr);

    // 8. FC2 + residual(x1) -> d_out
    gemm_kernel<EP_FC2, 1024, 4096, 64, 64, 64><<<1024, 256, 0, stream>>>(
        h_buf, fc2_wT, fc2b, x1, d_out, nullptr, nullptr, nullptr);
}